// Round 4
// baseline (406.604 us; speedup 1.0000x reference)
//
#include <hip/hip_runtime.h>

#define NN 50000
#define EE 800000
#define IND 128
#define EDD 32
#define ODD 16
#define NH 4
#define HD 64
#define NEG_SLOPE 0.2f
#define NBLK ((NN + 255) / 256)   // 196 scan blocks

typedef float  f32x4 __attribute__((ext_vector_type(4)));
typedef int    i32x2 __attribute__((ext_vector_type(2)));
typedef _Float16 f16x8 __attribute__((ext_vector_type(8)));

// ---------------- init+prep fused: deg=0; Wt transpose; w_ee fold ----------
__global__ __launch_bounds__(256)
void k_init_prep(int* __restrict__ deg, const float* __restrict__ W_fc,
                 const float* __restrict__ W_edge, const float* __restrict__ attn_e,
                 float* __restrict__ Wt, float* __restrict__ w_ee) {
    int i = blockIdx.x * 256 + threadIdx.x;
    if (i < NN) deg[i] = 0;
    if (i < HD * IND) {
        int k = i >> 6, j = i & 63;
        Wt[i] = W_fc[j * IND + k];
    }
    if (i < NH * EDD) {
        int h = i >> 5, k = i & 31;
        float s = 0.f;
        for (int d = 0; d < ODD; ++d)
            s += W_edge[(h * ODD + d) * EDD + k] * attn_e[h * ODD + d];
        w_ee[i] = s;
    }
}

// ------- node projection: gridDim.y=2 halves (block-uniform -> s_load weights)
// ------- full feat row prefetched (nontemporal stream); fp16 output rows
__global__ __launch_bounds__(256)
void k_node(const float* __restrict__ feat, const float* __restrict__ Wt,
            const float* __restrict__ attn_h, const float* __restrict__ attn_t,
            _Float16* __restrict__ feat_h, float2* __restrict__ eh2,
            float2* __restrict__ et2) {
    int n = blockIdx.x * 256 + threadIdx.x;
    int hf = blockIdx.y;                    // block-uniform -> scalar weight loads
    if (n >= NN) return;
    const int jbase = hf * 32;
    f32x4 row[32];
    const f32x4* fr4 = (const f32x4*)(feat + (long)n * IND);
#pragma unroll
    for (int q = 0; q < 32; ++q) row[q] = __builtin_nontemporal_load(fr4 + q);
    asm volatile("" ::: "memory");          // keep all 32 loads hoisted
    float acc[32];
#pragma unroll
    for (int j = 0; j < 32; ++j) acc[j] = 0.f;
#pragma unroll
    for (int k0 = 0; k0 < 32; ++k0) {
        float f[4] = {row[k0][0], row[k0][1], row[k0][2], row[k0][3]};
#pragma unroll
        for (int kk = 0; kk < 4; ++kk) {
            const float* w = Wt + (k0 * 4 + kk) * HD + jbase;  // wave-uniform
#pragma unroll
            for (int j = 0; j < 32; ++j) acc[j] += f[kk] * w[j];
        }
    }
    // fp16 pack: 32 halves = 4 x 16B stores
    f16x8* d8 = (f16x8*)(feat_h + (long)n * HD + jbase);
#pragma unroll
    for (int q = 0; q < 4; ++q) {
        f16x8 v;
#pragma unroll
        for (int j = 0; j < 8; ++j) v[j] = (_Float16)acc[q * 8 + j];
        d8[q] = v;
    }
    float sh[2], st[2];
#pragma unroll
    for (int hh = 0; hh < 2; ++hh) {
        sh[hh] = 0.f; st[hh] = 0.f;
        int hg = hf * 2 + hh;
#pragma unroll
        for (int d = 0; d < ODD; ++d) {
            float av = acc[hh * ODD + d];
            sh[hh] += av * attn_h[hg * ODD + d];
            st[hh] += av * attn_t[hg * ODD + d];
        }
    }
    eh2[n * 2 + hf] = make_float2(sh[0], sh[1]);
    et2[n * 2 + hf] = make_float2(st[0], st[1]);
}

// ---------------- histogram of dst (no rank store) --------------------------
__global__ __launch_bounds__(256)
void k_hist(const int* __restrict__ dst, int* __restrict__ deg) {
    int e = blockIdx.x * 256 + threadIdx.x;
    if (e < EE) atomicAdd(&deg[__builtin_nontemporal_load(dst + e)], 1);
}

// ---------------- two-level exclusive scan of deg -> offs (+cursor copy) ----
__global__ __launch_bounds__(256)
void k_scan1(const int* __restrict__ deg, int* __restrict__ offs, int* __restrict__ part) {
    __shared__ int s[256];
    int t = threadIdx.x, i = blockIdx.x * 256 + t;
    int v = (i < NN) ? deg[i] : 0;
    s[t] = v;
    __syncthreads();
#pragma unroll
    for (int o = 1; o < 256; o <<= 1) {
        int u = (t >= o) ? s[t - o] : 0;
        __syncthreads();
        if (t >= o) s[t] += u;
        __syncthreads();
    }
    if (i < NN) offs[i] = s[t] - v;
    if (t == 255) part[blockIdx.x] = s[255];
}

__global__ __launch_bounds__(256)
void k_scan2(int* __restrict__ part) {
    __shared__ int s[256];
    int t = threadIdx.x;
    int v = (t < NBLK) ? part[t] : 0;
    s[t] = v;
    __syncthreads();
#pragma unroll
    for (int o = 1; o < 256; o <<= 1) {
        int u = (t >= o) ? s[t - o] : 0;
        __syncthreads();
        if (t >= o) s[t] += u;
        __syncthreads();
    }
    if (t < NBLK) part[t] = s[t] - v;
}

__global__ __launch_bounds__(256)
void k_scan3(int* __restrict__ offs, int* __restrict__ cursor,
             const int* __restrict__ part) {
    int i = blockIdx.x * 256 + threadIdx.x;
    if (i < NN) {
        int v = offs[i] + part[i >> 8];
        offs[i] = v;
        cursor[i] = v;      // k_perm's atomic cursor starts at offs
    }
}

// ------- PURE STREAM edge MLP: za[e] = edge_attr @ w_ee.T (f32x4, no randoms)
__global__ __launch_bounds__(256)
void k_ee(const float* __restrict__ edge_attr, const float* __restrict__ w_ee,
          f32x4* __restrict__ za4) {
    int t = blockIdx.x * 256 + threadIdx.x;
    int e0 = t * 2;
    if (e0 >= EE) return;
    const f32x4* ea = (const f32x4*)(edge_attr + (long)e0 * EDD);
    f32x4 r[16];
#pragma unroll
    for (int c = 0; c < 16; ++c) r[c] = __builtin_nontemporal_load(ea + c);
    asm volatile("" ::: "memory");
    const float* f0 = (const float*)&r[0];
    const float* f1 = (const float*)&r[8];
    f32x4 z0, z1;
#pragma unroll
    for (int h = 0; h < NH; ++h) {
        float a = 0.f, b = 0.f;
#pragma unroll
        for (int k = 0; k < EDD; ++k) {
            float w = w_ee[h * EDD + k];    // uniform -> s_load
            a += f0[k] * w;
            b += f1[k] * w;
        }
        z0[h] = a; z1[h] = b;
    }
    __builtin_nontemporal_store(z0, za4 + e0);
    __builtin_nontemporal_store(z1, za4 + e0 + 1);
}

// ------- PURE RANDOM perm pass: atomic cursor + 8B {e,src} scatter ----------
__global__ __launch_bounds__(256)
void k_perm(const int* __restrict__ dst, const int* __restrict__ src,
            int* __restrict__ cursor, i32x2* __restrict__ perm2) {
    int e = blockIdx.x * 256 + threadIdx.x;
    if (e >= EE) return;
    int d = __builtin_nontemporal_load(dst + e);
    int s = __builtin_nontemporal_load(src + e);
    int pos = atomicAdd(&cursor[d], 1);     // replaces offs gather + rank
    i32x2 rec = {e, s};
    __builtin_nontemporal_store(rec, perm2 + pos);   // one 8B scatter/edge
}

// ------- per-dst reduce: perm2 stream carries src; za + eh gathers ----------
__global__ __launch_bounds__(256)
void k_reduce(const int* __restrict__ offs, const int* __restrict__ deg,
              const f32x4* __restrict__ za4, const i32x2* __restrict__ perm2,
              const float* __restrict__ eh, const float* __restrict__ et,
              const _Float16* __restrict__ feat_h, const float* __restrict__ bias,
              float* __restrict__ out) {
    int wid = (blockIdx.x * 256 + threadIdx.x) >> 6;   // one wave per dst node
    int lane = threadIdx.x & 63;
    if (wid >= NN) return;
    int start = __builtin_amdgcn_readfirstlane(offs[wid]);
    int dn    = __builtin_amdgcn_readfirstlane(deg[wid]);
    int h = lane >> 4;          // head of this lane
    int q = lane & 15;          // edge slot within chunk
    float et_h = et[(long)wid * 4 + h];                // wave-level uniform
    float acc = 0.f, l = 0.f;

    for (int c0 = 0; c0 < dn; c0 += 16) {
        int rem = dn - c0; if (rem > 16) rem = 16;
        int qq = (q < rem) ? q : (rem - 1);            // clamp: stay in-bounds
        i32x2 p = perm2[start + c0 + qq];              // coalesced (2 lines/wave)
        int e_q = p.x, s_q = p.y;                      // src WITHOUT extra gather
        float z   = za4[e_q][h];                       // random 4B (merged line)
        float ehv = eh[(long)s_q * 4 + h];             // random 4B (L2-hot)
        float x = z + ehv + et_h;
        x = x > 0.f ? x : NEG_SLOPE * x;
        float a_q = (q < rem) ? __expf(x) : 0.f;       // no max-shift: 0.1-scale
        float f[16];
#pragma unroll
        for (int i = 0; i < 16; ++i) {
            int si = __shfl(s_q, i);                   // edge i's src (quad 0)
            f[i] = (float)feat_h[(long)si * HD + lane]; // coalesced 128B row gather
        }
#pragma unroll
        for (int i = 0; i < 16; ++i) {
            float ai = __shfl(a_q, (lane & 48) + i);   // edge i, this lane's head
            l += ai;
            acc += ai * f[i];
        }
    }
    float res = (l > 0.f) ? acc / l : 0.f;
    __builtin_nontemporal_store(res + bias[lane], &out[(long)wid * HD + lane]);
}

extern "C" void kernel_launch(void* const* d_in, const int* in_sizes, int n_in,
                              void* d_out, int out_size, void* d_ws, size_t ws_size,
                              hipStream_t stream) {
    const float* feat      = (const float*)d_in[0];
    const float* edge_attr = (const float*)d_in[1];
    const int*   src       = (const int*)d_in[2];
    const int*   dst       = (const int*)d_in[3];
    const float* W_fc      = (const float*)d_in[4];
    const float* W_edge    = (const float*)d_in[5];
    const float* attn_h    = (const float*)d_in[6];
    const float* attn_t    = (const float*)d_in[7];
    const float* attn_e    = (const float*)d_in[8];
    const float* bias      = (const float*)d_in[9];
    float* out             = (float*)d_out;

    float* ws        = (float*)d_ws;
    f32x4*  za4      = (f32x4*)ws;                     // E*16B (12.8 MB)
    float4* eh4      = (float4*)(za4 + EE);            // N*4
    float4* et4      = eh4 + NN;                       // N*4
    _Float16* feat_h = (_Float16*)(et4 + NN);          // N*64 halves (6.4 MB)
    float*  Wt       = (float*)(feat_h + (long)NN * HD); // 8192
    float*  w_ee     = Wt + HD * IND;                  // 128
    i32x2*  perm2    = (i32x2*)(w_ee + NH * EDD);      // E*8B (6.4 MB)
    int*    deg      = (int*)(perm2 + EE);             // N
    int*    offs     = deg + NN;                       // N
    int*    cursor   = offs + NN;                      // N
    int*    part     = cursor + NN;                    // NBLK
    // total ~ 28 MB of d_ws

    k_init_prep<<<NBLK, 256, 0, stream>>>(deg, W_fc, W_edge, attn_e, Wt, w_ee);
    dim3 ngrid(NBLK, 2);
    k_node<<<ngrid, 256, 0, stream>>>(feat, Wt, attn_h, attn_t, feat_h,
                                      (float2*)eh4, (float2*)et4);
    k_ee<<<(EE / 2 + 255) / 256, 256, 0, stream>>>(edge_attr, w_ee, za4);
    k_hist<<<(EE + 255) / 256, 256, 0, stream>>>(dst, deg);
    k_scan1<<<NBLK, 256, 0, stream>>>(deg, offs, part);
    k_scan2<<<1, 256, 0, stream>>>(part);
    k_scan3<<<NBLK, 256, 0, stream>>>(offs, cursor, part);
    k_perm<<<(EE + 255) / 256, 256, 0, stream>>>(dst, src, cursor, perm2);
    k_reduce<<<(NN * 64 + 255) / 256, 256, 0, stream>>>(offs, deg, za4, perm2,
                                                        (const float*)eh4,
                                                        (const float*)et4,
                                                        feat_h, bias, out);
}

// Round 5
// 378.292 us; speedup vs baseline: 1.0748x; 1.0748x over previous
//
#include <hip/hip_runtime.h>

#define NN 50000
#define EE 800000
#define IND 128
#define EDD 32
#define ODD 16
#define NH 4
#define HD 64
#define NEG_SLOPE 0.2f
#define NBLK ((NN + 255) / 256)   // 196 scan blocks

typedef float  f32x4 __attribute__((ext_vector_type(4)));
typedef int    i32x2 __attribute__((ext_vector_type(2)));
typedef int    i32x4 __attribute__((ext_vector_type(4)));
typedef _Float16 f16x8 __attribute__((ext_vector_type(8)));

union h2i { int i; _Float16 h[2]; };

// ---------------- init+prep fused: deg=0; Wt transpose; w_ee fold ----------
__global__ __launch_bounds__(256)
void k_init_prep(int* __restrict__ deg, const float* __restrict__ W_fc,
                 const float* __restrict__ W_edge, const float* __restrict__ attn_e,
                 float* __restrict__ Wt, float* __restrict__ w_ee) {
    int i = blockIdx.x * 256 + threadIdx.x;
    if (i < NN) deg[i] = 0;
    if (i < HD * IND) {
        int k = i >> 6, j = i & 63;
        Wt[i] = W_fc[j * IND + k];
    }
    if (i < NH * EDD) {
        int h = i >> 5, k = i & 31;
        float s = 0.f;
        for (int d = 0; d < ODD; ++d)
            s += W_edge[(h * ODD + d) * EDD + k] * attn_e[h * ODD + d];
        w_ee[i] = s;
    }
}

// ------- node projection: gridDim.y=2 halves (block-uniform -> s_load weights)
// ------- full feat row prefetched; fp16 output rows (proven: absmax 0.0078)
__global__ __launch_bounds__(256)
void k_node(const float* __restrict__ feat, const float* __restrict__ Wt,
            const float* __restrict__ attn_h, const float* __restrict__ attn_t,
            _Float16* __restrict__ feat_h, float2* __restrict__ eh2,
            float2* __restrict__ et2) {
    int n = blockIdx.x * 256 + threadIdx.x;
    int hf = blockIdx.y;                    // block-uniform -> scalar weight loads
    if (n >= NN) return;
    const int jbase = hf * 32;
    f32x4 row[32];
    const f32x4* fr4 = (const f32x4*)(feat + (long)n * IND);
#pragma unroll
    for (int q = 0; q < 32; ++q) row[q] = __builtin_nontemporal_load(fr4 + q);
    asm volatile("" ::: "memory");          // keep all 32 loads hoisted
    float acc[32];
#pragma unroll
    for (int j = 0; j < 32; ++j) acc[j] = 0.f;
#pragma unroll
    for (int k0 = 0; k0 < 32; ++k0) {
        float f[4] = {row[k0][0], row[k0][1], row[k0][2], row[k0][3]};
#pragma unroll
        for (int kk = 0; kk < 4; ++kk) {
            const float* w = Wt + (k0 * 4 + kk) * HD + jbase;  // wave-uniform
#pragma unroll
            for (int j = 0; j < 32; ++j) acc[j] += f[kk] * w[j];
        }
    }
    // fp16 pack: 32 halves = 4 x 16B stores
    f16x8* d8 = (f16x8*)(feat_h + (long)n * HD + jbase);
#pragma unroll
    for (int q = 0; q < 4; ++q) {
        f16x8 v;
#pragma unroll
        for (int j = 0; j < 8; ++j) v[j] = (_Float16)acc[q * 8 + j];
        d8[q] = v;
    }
    float sh[2], st[2];
#pragma unroll
    for (int hh = 0; hh < 2; ++hh) {
        sh[hh] = 0.f; st[hh] = 0.f;
        int hg = hf * 2 + hh;
#pragma unroll
        for (int d = 0; d < ODD; ++d) {
            float av = acc[hh * ODD + d];
            sh[hh] += av * attn_h[hg * ODD + d];
            st[hh] += av * attn_t[hg * ODD + d];
        }
    }
    eh2[n * 2 + hf] = make_float2(sh[0], sh[1]);
    et2[n * 2 + hf] = make_float2(st[0], st[1]);
}

// ---------------- histogram of dst + per-edge rank --------------------------
__global__ __launch_bounds__(256)
void k_hist(const int* __restrict__ dst, int* __restrict__ deg, int* __restrict__ rank) {
    int e = blockIdx.x * 256 + threadIdx.x;
    if (e < EE) rank[e] = atomicAdd(&deg[dst[e]], 1);
}

// ---------------- two-level exclusive scan of deg -> offs -------------------
__global__ __launch_bounds__(256)
void k_scan1(const int* __restrict__ deg, int* __restrict__ offs, int* __restrict__ part) {
    __shared__ int s[256];
    int t = threadIdx.x, i = blockIdx.x * 256 + t;
    int v = (i < NN) ? deg[i] : 0;
    s[t] = v;
    __syncthreads();
#pragma unroll
    for (int o = 1; o < 256; o <<= 1) {
        int u = (t >= o) ? s[t - o] : 0;
        __syncthreads();
        if (t >= o) s[t] += u;
        __syncthreads();
    }
    if (i < NN) offs[i] = s[t] - v;
    if (t == 255) part[blockIdx.x] = s[255];
}

__global__ __launch_bounds__(256)
void k_scan2(int* __restrict__ part) {
    __shared__ int s[256];
    int t = threadIdx.x;
    int v = (t < NBLK) ? part[t] : 0;
    s[t] = v;
    __syncthreads();
#pragma unroll
    for (int o = 1; o < 256; o <<= 1) {
        int u = (t >= o) ? s[t - o] : 0;
        __syncthreads();
        if (t >= o) s[t] += u;
        __syncthreads();
    }
    if (t < NBLK) part[t] = s[t] - v;
}

__global__ __launch_bounds__(256)
void k_scan3(int* __restrict__ offs, const int* __restrict__ part) {
    int i = blockIdx.x * 256 + threadIdx.x;
    if (i < NN) offs[i] += part[i >> 8];
}

// ------- edge MLP (2 edges/thread), round-0 structure -----------------------
// rec[e] = {src, z01(2xf16), z23(2xf16), 0}: coalesced 16B write by edge index.
// Random ops: offs gathers (L2-hot 0.2MB) + 4B perm scatters — same as the
// 336us baseline. NO node-indexed gathers, NO exp here.
__global__ __launch_bounds__(256)
void k_logit2(const float* __restrict__ edge_attr, const int* __restrict__ dst,
              const int* __restrict__ src, const float* __restrict__ w_ee,
              const int* __restrict__ offs, const int* __restrict__ rank,
              i32x4* __restrict__ rec4, int* __restrict__ perm) {
    int t = blockIdx.x * 256 + threadIdx.x;
    int e0 = t * 2;
    if (e0 >= EE) return;
    i32x2 d2 = *(const i32x2*)(dst + e0);
    i32x2 r2 = *(const i32x2*)(rank + e0);
    i32x2 s2 = *(const i32x2*)(src + e0);
    int o0 = offs[d2[0]], o1 = offs[d2[1]];
    const f32x4* ea = (const f32x4*)(edge_attr + (long)e0 * EDD);
    f32x4 r[16];
#pragma unroll
    for (int c = 0; c < 16; ++c) r[c] = __builtin_nontemporal_load(ea + c);
    asm volatile("" ::: "memory");
    const float* f0 = (const float*)&r[0];
    const float* f1 = (const float*)&r[8];
    float z0[NH], z1[NH];
#pragma unroll
    for (int h = 0; h < NH; ++h) {
        float a = 0.f, b = 0.f;
#pragma unroll
        for (int k = 0; k < EDD; ++k) {
            float w = w_ee[h * EDD + k];    // uniform -> s_load
            a += f0[k] * w;
            b += f1[k] * w;
        }
        z0[h] = a; z1[h] = b;
    }
    h2i p01, p23, q01, q23;
    p01.h[0] = (_Float16)z0[0]; p01.h[1] = (_Float16)z0[1];
    p23.h[0] = (_Float16)z0[2]; p23.h[1] = (_Float16)z0[3];
    q01.h[0] = (_Float16)z1[0]; q01.h[1] = (_Float16)z1[1];
    q23.h[0] = (_Float16)z1[2]; q23.h[1] = (_Float16)z1[3];
    i32x4 rc0 = {s2[0], p01.i, p23.i, 0};
    i32x4 rc1 = {s2[1], q01.i, q23.i, 0};
    __builtin_nontemporal_store(rc0, rec4 + e0);     // coalesced
    __builtin_nontemporal_store(rc1, rec4 + e0 + 1);
    perm[o0 + r2[0]] = e0;                           // only 4B scatters
    perm[o1 + r2[1]] = e0 + 1;
}

// ------- per-dst reduce: rec carries src+z -> one fewer random class --------
// Random per edge: rec (16B) + eh[src] (4B, 0.8MB L2-hot) + fp16 row (128B).
__global__ __launch_bounds__(256)
void k_reduce(const int* __restrict__ offs, const int* __restrict__ deg,
              const i32x4* __restrict__ rec4, const int* __restrict__ perm,
              const float* __restrict__ eh, const float* __restrict__ et,
              const _Float16* __restrict__ feat_h, const float* __restrict__ bias,
              float* __restrict__ out) {
    int wid = (blockIdx.x * 256 + threadIdx.x) >> 6;   // one wave per dst node
    int lane = threadIdx.x & 63;
    if (wid >= NN) return;
    int start = __builtin_amdgcn_readfirstlane(offs[wid]);
    int dn    = __builtin_amdgcn_readfirstlane(deg[wid]);
    int h = lane >> 4;          // head of this lane
    int q = lane & 15;          // edge slot within chunk
    float et_h = et[(long)wid * 4 + h];                // wave-level uniform
    float acc = 0.f, l = 0.f;

    for (int c0 = 0; c0 < dn; c0 += 16) {
        int rem = dn - c0; if (rem > 16) rem = 16;
        int qq = (q < rem) ? q : (rem - 1);            // clamp: stay in-bounds
        int   e_q = perm[start + c0 + qq];             // coalesced (1 line/wave)
        i32x4 r   = rec4[e_q];                         // ONE random 16B gather
        int   s_q = r.x;
        h2i u; u.i = (h & 2) ? r.z : r.y;
        float z = (float)u.h[h & 1];
        float x = z + eh[(long)s_q * 4 + h] + et_h;    // eh: random 4B, L2-hot
        x = x > 0.f ? x : NEG_SLOPE * x;
        float a_q = (q < rem) ? __expf(x) : 0.f;       // no max-shift: 0.1-scale
        float f[16];
#pragma unroll
        for (int i = 0; i < 16; ++i) {
            int si = __shfl(s_q, i);                   // edge i's src (quad 0)
            f[i] = (float)feat_h[(long)si * HD + lane]; // coalesced 128B row gather
        }
#pragma unroll
        for (int i = 0; i < 16; ++i) {
            float ai = __shfl(a_q, (lane & 48) + i);   // edge i, this lane's head
            l += ai;
            acc += ai * f[i];
        }
    }
    float res = (l > 0.f) ? acc / l : 0.f;
    __builtin_nontemporal_store(res + bias[lane], &out[(long)wid * HD + lane]);
}

extern "C" void kernel_launch(void* const* d_in, const int* in_sizes, int n_in,
                              void* d_out, int out_size, void* d_ws, size_t ws_size,
                              hipStream_t stream) {
    const float* feat      = (const float*)d_in[0];
    const float* edge_attr = (const float*)d_in[1];
    const int*   src       = (const int*)d_in[2];
    const int*   dst       = (const int*)d_in[3];
    const float* W_fc      = (const float*)d_in[4];
    const float* W_edge    = (const float*)d_in[5];
    const float* attn_h    = (const float*)d_in[6];
    const float* attn_t    = (const float*)d_in[7];
    const float* attn_e    = (const float*)d_in[8];
    const float* bias      = (const float*)d_in[9];
    float* out             = (float*)d_out;

    float* ws        = (float*)d_ws;
    i32x4*  rec4     = (i32x4*)ws;                     // E*16B (12.8 MB)
    float4* eh4      = (float4*)(rec4 + EE);           // N*4
    float4* et4      = eh4 + NN;                       // N*4
    _Float16* feat_h = (_Float16*)(et4 + NN);          // N*64 halves (6.4 MB)
    float*  Wt       = (float*)(feat_h + (long)NN * HD); // 8192
    float*  w_ee     = Wt + HD * IND;                  // 128
    int*    perm     = (int*)(w_ee + NH * EDD);        // E
    int*    rank     = perm + EE;                      // E
    int*    deg      = rank + EE;                      // N
    int*    offs     = deg + NN;                       // N
    int*    part     = offs + NN;                      // NBLK
    // total ~ 29 MB of d_ws

    k_init_prep<<<NBLK, 256, 0, stream>>>(deg, W_fc, W_edge, attn_e, Wt, w_ee);
    dim3 ngrid(NBLK, 2);
    k_node<<<ngrid, 256, 0, stream>>>(feat, Wt, attn_h, attn_t, feat_h,
                                      (float2*)eh4, (float2*)et4);
    k_hist<<<(EE + 255) / 256, 256, 0, stream>>>(dst, deg, rank);
    k_scan1<<<NBLK, 256, 0, stream>>>(deg, offs, part);
    k_scan2<<<1, 256, 0, stream>>>(part);
    k_scan3<<<NBLK, 256, 0, stream>>>(offs, part);
    k_logit2<<<(EE / 2 + 255) / 256, 256, 0, stream>>>(edge_attr, dst, src, w_ee,
                                                       offs, rank, rec4, perm);
    k_reduce<<<(NN * 64 + 255) / 256, 256, 0, stream>>>(offs, deg, rec4, perm,
                                                        (const float*)eh4,
                                                        (const float*)et4,
                                                        feat_h, bias, out);
}

// Round 6
// 351.482 us; speedup vs baseline: 1.1568x; 1.0763x over previous
//
#include <hip/hip_runtime.h>

#define NN 50000
#define EE 800000
#define IND 128
#define EDD 32
#define ODD 16
#define NH 4
#define HD 64
#define NEG_SLOPE 0.2f
#define NBLK ((NN + 255) / 256)   // 196 scan blocks

typedef float  f32x4 __attribute__((ext_vector_type(4)));
typedef int    i32x2 __attribute__((ext_vector_type(2)));
typedef int    i32x4 __attribute__((ext_vector_type(4)));
typedef _Float16 f16x8 __attribute__((ext_vector_type(8)));

union h2i { int i; _Float16 h[2]; };

// ---------------- init+prep fused: deg=0; Wt transpose; w_ee fold ----------
__global__ __launch_bounds__(256)
void k_init_prep(int* __restrict__ deg, const float* __restrict__ W_fc,
                 const float* __restrict__ W_edge, const float* __restrict__ attn_e,
                 float* __restrict__ Wt, float* __restrict__ w_ee) {
    int i = blockIdx.x * 256 + threadIdx.x;
    if (i < NN) deg[i] = 0;
    if (i < HD * IND) {
        int k = i >> 6, j = i & 63;
        Wt[i] = W_fc[j * IND + k];
    }
    if (i < NH * EDD) {
        int h = i >> 5, k = i & 31;
        float s = 0.f;
        for (int d = 0; d < ODD; ++d)
            s += W_edge[(h * ODD + d) * EDD + k] * attn_e[h * ODD + d];
        w_ee[i] = s;
    }
}

// ------- node projection: gridDim.y=2 halves (block-uniform -> s_load weights)
// ------- full feat row prefetched; fp16 output rows (proven: absmax 0.0078)
__global__ __launch_bounds__(256)
void k_node(const float* __restrict__ feat, const float* __restrict__ Wt,
            const float* __restrict__ attn_h, const float* __restrict__ attn_t,
            _Float16* __restrict__ feat_h, float2* __restrict__ eh2,
            float2* __restrict__ et2) {
    int n = blockIdx.x * 256 + threadIdx.x;
    int hf = blockIdx.y;                    // block-uniform -> scalar weight loads
    if (n >= NN) return;
    const int jbase = hf * 32;
    f32x4 row[32];
    const f32x4* fr4 = (const f32x4*)(feat + (long)n * IND);
#pragma unroll
    for (int q = 0; q < 32; ++q) row[q] = __builtin_nontemporal_load(fr4 + q);
    asm volatile("" ::: "memory");          // keep all 32 loads hoisted
    float acc[32];
#pragma unroll
    for (int j = 0; j < 32; ++j) acc[j] = 0.f;
#pragma unroll
    for (int k0 = 0; k0 < 32; ++k0) {
        float f[4] = {row[k0][0], row[k0][1], row[k0][2], row[k0][3]};
#pragma unroll
        for (int kk = 0; kk < 4; ++kk) {
            const float* w = Wt + (k0 * 4 + kk) * HD + jbase;  // wave-uniform
#pragma unroll
            for (int j = 0; j < 32; ++j) acc[j] += f[kk] * w[j];
        }
    }
    // fp16 pack: 32 halves = 4 x 16B stores
    f16x8* d8 = (f16x8*)(feat_h + (long)n * HD + jbase);
#pragma unroll
    for (int q = 0; q < 4; ++q) {
        f16x8 v;
#pragma unroll
        for (int j = 0; j < 8; ++j) v[j] = (_Float16)acc[q * 8 + j];
        d8[q] = v;
    }
    float sh[2], st[2];
#pragma unroll
    for (int hh = 0; hh < 2; ++hh) {
        sh[hh] = 0.f; st[hh] = 0.f;
        int hg = hf * 2 + hh;
#pragma unroll
        for (int d = 0; d < ODD; ++d) {
            float av = acc[hh * ODD + d];
            sh[hh] += av * attn_h[hg * ODD + d];
            st[hh] += av * attn_t[hg * ODD + d];
        }
    }
    eh2[n * 2 + hf] = make_float2(sh[0], sh[1]);
    et2[n * 2 + hf] = make_float2(st[0], st[1]);
}

// ---------------- histogram of dst + per-edge rank --------------------------
__global__ __launch_bounds__(256)
void k_hist(const int* __restrict__ dst, int* __restrict__ deg, int* __restrict__ rank) {
    int e = blockIdx.x * 256 + threadIdx.x;
    if (e < EE) rank[e] = atomicAdd(&deg[dst[e]], 1);
}

// ---------------- two-level exclusive scan of deg -> offs -------------------
__global__ __launch_bounds__(256)
void k_scan1(const int* __restrict__ deg, int* __restrict__ offs, int* __restrict__ part) {
    __shared__ int s[256];
    int t = threadIdx.x, i = blockIdx.x * 256 + t;
    int v = (i < NN) ? deg[i] : 0;
    s[t] = v;
    __syncthreads();
#pragma unroll
    for (int o = 1; o < 256; o <<= 1) {
        int u = (t >= o) ? s[t - o] : 0;
        __syncthreads();
        if (t >= o) s[t] += u;
        __syncthreads();
    }
    if (i < NN) offs[i] = s[t] - v;
    if (t == 255) part[blockIdx.x] = s[255];
}

__global__ __launch_bounds__(256)
void k_scan2(int* __restrict__ part) {
    __shared__ int s[256];
    int t = threadIdx.x;
    int v = (t < NBLK) ? part[t] : 0;
    s[t] = v;
    __syncthreads();
#pragma unroll
    for (int o = 1; o < 256; o <<= 1) {
        int u = (t >= o) ? s[t - o] : 0;
        __syncthreads();
        if (t >= o) s[t] += u;
        __syncthreads();
    }
    if (t < NBLK) part[t] = s[t] - v;
}

__global__ __launch_bounds__(256)
void k_scan3(int* __restrict__ offs, const int* __restrict__ part) {
    int i = blockIdx.x * 256 + threadIdx.x;
    if (i < NN) offs[i] += part[i >> 8];
}

// ------- edge MLP (2 edges/thread), round-0 structure, PLAIN loads/stores ---
// rec[e] = {src, z01(2xf16), z23(2xf16), 0}: coalesced 16B write by edge index
// (plain store -> stays L2-resident for k_reduce's random gathers).
// Random ops: offs gathers (L2-hot 0.2MB) + 4B perm scatters only.
__global__ __launch_bounds__(256)
void k_logit2(const float* __restrict__ edge_attr, const int* __restrict__ dst,
              const int* __restrict__ src, const float* __restrict__ w_ee,
              const int* __restrict__ offs, const int* __restrict__ rank,
              i32x4* __restrict__ rec4, int* __restrict__ perm) {
    int t = blockIdx.x * 256 + threadIdx.x;
    int e0 = t * 2;
    if (e0 >= EE) return;
    i32x2 d2 = *(const i32x2*)(dst + e0);
    i32x2 r2 = *(const i32x2*)(rank + e0);
    i32x2 s2 = *(const i32x2*)(src + e0);
    int o0 = offs[d2[0]], o1 = offs[d2[1]];
    const f32x4* ea = (const f32x4*)(edge_attr + (long)e0 * EDD);
    f32x4 r[16];
#pragma unroll
    for (int c = 0; c < 16; ++c) r[c] = ea[c];       // plain loads (round-0)
    asm volatile("" ::: "memory");
    const float* f0 = (const float*)&r[0];
    const float* f1 = (const float*)&r[8];
    float z0[NH], z1[NH];
#pragma unroll
    for (int h = 0; h < NH; ++h) {
        float a = 0.f, b = 0.f;
#pragma unroll
        for (int k = 0; k < EDD; ++k) {
            float w = w_ee[h * EDD + k];    // uniform -> s_load
            a += f0[k] * w;
            b += f1[k] * w;
        }
        z0[h] = a; z1[h] = b;
    }
    h2i p01, p23, q01, q23;
    p01.h[0] = (_Float16)z0[0]; p01.h[1] = (_Float16)z0[1];
    p23.h[0] = (_Float16)z0[2]; p23.h[1] = (_Float16)z0[3];
    q01.h[0] = (_Float16)z1[0]; q01.h[1] = (_Float16)z1[1];
    q23.h[0] = (_Float16)z1[2]; q23.h[1] = (_Float16)z1[3];
    i32x4 rc0 = {s2[0], p01.i, p23.i, 0};
    i32x4 rc1 = {s2[1], q01.i, q23.i, 0};
    rec4[e0]     = rc0;                              // plain coalesced stores
    rec4[e0 + 1] = rc1;
    perm[o0 + r2[0]] = e0;                           // only 4B scatters
    perm[o1 + r2[1]] = e0 + 1;
}

// ------- per-dst reduce: rec carries src+z -> one fewer random class --------
// Random per edge: rec (16B, L2-warm) + eh[src] (4B, 0.8MB L2-hot) + fp16 row.
__global__ __launch_bounds__(256)
void k_reduce(const int* __restrict__ offs, const int* __restrict__ deg,
              const i32x4* __restrict__ rec4, const int* __restrict__ perm,
              const float* __restrict__ eh, const float* __restrict__ et,
              const _Float16* __restrict__ feat_h, const float* __restrict__ bias,
              float* __restrict__ out) {
    int wid = (blockIdx.x * 256 + threadIdx.x) >> 6;   // one wave per dst node
    int lane = threadIdx.x & 63;
    if (wid >= NN) return;
    int start = __builtin_amdgcn_readfirstlane(offs[wid]);
    int dn    = __builtin_amdgcn_readfirstlane(deg[wid]);
    int h = lane >> 4;          // head of this lane
    int q = lane & 15;          // edge slot within chunk
    float et_h = et[(long)wid * 4 + h];                // wave-level uniform
    float acc = 0.f, l = 0.f;

    for (int c0 = 0; c0 < dn; c0 += 16) {
        int rem = dn - c0; if (rem > 16) rem = 16;
        int qq = (q < rem) ? q : (rem - 1);            // clamp: stay in-bounds
        int   e_q = perm[start + c0 + qq];             // coalesced (1 line/wave)
        i32x4 r   = rec4[e_q];                         // ONE random 16B gather
        int   s_q = r.x;
        h2i u; u.i = (h & 2) ? r.z : r.y;
        float z = (float)u.h[h & 1];
        float x = z + eh[(long)s_q * 4 + h] + et_h;    // eh: random 4B, L2-hot
        x = x > 0.f ? x : NEG_SLOPE * x;
        float a_q = (q < rem) ? __expf(x) : 0.f;       // no max-shift: 0.1-scale
        float f[16];
#pragma unroll
        for (int i = 0; i < 16; ++i) {
            int si = __shfl(s_q, i);                   // edge i's src (quad 0)
            f[i] = (float)feat_h[(long)si * HD + lane]; // coalesced 128B row gather
        }
#pragma unroll
        for (int i = 0; i < 16; ++i) {
            float ai = __shfl(a_q, (lane & 48) + i);   // edge i, this lane's head
            l += ai;
            acc += ai * f[i];
        }
    }
    float res = (l > 0.f) ? acc / l : 0.f;
    __builtin_nontemporal_store(res + bias[lane], &out[(long)wid * HD + lane]);
}

extern "C" void kernel_launch(void* const* d_in, const int* in_sizes, int n_in,
                              void* d_out, int out_size, void* d_ws, size_t ws_size,
                              hipStream_t stream) {
    const float* feat      = (const float*)d_in[0];
    const float* edge_attr = (const float*)d_in[1];
    const int*   src       = (const int*)d_in[2];
    const int*   dst       = (const int*)d_in[3];
    const float* W_fc      = (const float*)d_in[4];
    const float* W_edge    = (const float*)d_in[5];
    const float* attn_h    = (const float*)d_in[6];
    const float* attn_t    = (const float*)d_in[7];
    const float* attn_e    = (const float*)d_in[8];
    const float* bias      = (const float*)d_in[9];
    float* out             = (float*)d_out;

    float* ws        = (float*)d_ws;
    i32x4*  rec4     = (i32x4*)ws;                     // E*16B (12.8 MB)
    float4* eh4      = (float4*)(rec4 + EE);           // N*4
    float4* et4      = eh4 + NN;                       // N*4
    _Float16* feat_h = (_Float16*)(et4 + NN);          // N*64 halves (6.4 MB)
    float*  Wt       = (float*)(feat_h + (long)NN * HD); // 8192
    float*  w_ee     = Wt + HD * IND;                  // 128
    int*    perm     = (int*)(w_ee + NH * EDD);        // E
    int*    rank     = perm + EE;                      // E
    int*    deg      = rank + EE;                      // N
    int*    offs     = deg + NN;                       // N
    int*    part     = offs + NN;                      // NBLK
    // total ~ 29 MB of d_ws

    k_init_prep<<<NBLK, 256, 0, stream>>>(deg, W_fc, W_edge, attn_e, Wt, w_ee);
    dim3 ngrid(NBLK, 2);
    k_node<<<ngrid, 256, 0, stream>>>(feat, Wt, attn_h, attn_t, feat_h,
                                      (float2*)eh4, (float2*)et4);
    k_hist<<<(EE + 255) / 256, 256, 0, stream>>>(dst, deg, rank);
    k_scan1<<<NBLK, 256, 0, stream>>>(deg, offs, part);
    k_scan2<<<1, 256, 0, stream>>>(part);
    k_scan3<<<NBLK, 256, 0, stream>>>(offs, part);
    k_logit2<<<(EE / 2 + 255) / 256, 256, 0, stream>>>(edge_attr, dst, src, w_ee,
                                                       offs, rank, rec4, perm);
    k_reduce<<<(NN * 64 + 255) / 256, 256, 0, stream>>>(offs, deg, rec4, perm,
                                                        (const float*)eh4,
                                                        (const float*)et4,
                                                        feat_h, bias, out);
}

// Round 7
// 348.096 us; speedup vs baseline: 1.1681x; 1.0097x over previous
//
#include <hip/hip_runtime.h>

#define NN 50000
#define EE 800000
#define IND 128
#define EDD 32
#define ODD 16
#define NH 4
#define HD 64
#define NEG_SLOPE 0.2f
#define NBLK ((NN + 255) / 256)   // 196 scan blocks

typedef float  f32x4 __attribute__((ext_vector_type(4)));
typedef int    i32x2 __attribute__((ext_vector_type(2)));
typedef int    i32x4 __attribute__((ext_vector_type(4)));
typedef _Float16 f16x8 __attribute__((ext_vector_type(8)));

union h2i { int i; _Float16 h[2]; };

// ---------------- init+prep fused: deg=0; Wt transpose; w_ee fold ----------
__global__ __launch_bounds__(256)
void k_init_prep(int* __restrict__ deg, const float* __restrict__ W_fc,
                 const float* __restrict__ W_edge, const float* __restrict__ attn_e,
                 float* __restrict__ Wt, float* __restrict__ w_ee) {
    int i = blockIdx.x * 256 + threadIdx.x;
    if (i < NN) deg[i] = 0;
    if (i < HD * IND) {
        int k = i >> 6, j = i & 63;
        Wt[i] = W_fc[j * IND + k];
    }
    if (i < NH * EDD) {
        int h = i >> 5, k = i & 31;
        float s = 0.f;
        for (int d = 0; d < ODD; ++d)
            s += W_edge[(h * ODD + d) * EDD + k] * attn_e[h * ODD + d];
        w_ee[i] = s;
    }
}

// ------- node projection: gridDim.y=2 halves (block-uniform -> s_load weights)
// ------- full feat row prefetched; fp16 output rows (proven: absmax 0.0078)
__global__ __launch_bounds__(256)
void k_node(const float* __restrict__ feat, const float* __restrict__ Wt,
            const float* __restrict__ attn_h, const float* __restrict__ attn_t,
            _Float16* __restrict__ feat_h, float2* __restrict__ eh2,
            float2* __restrict__ et2) {
    int n = blockIdx.x * 256 + threadIdx.x;
    int hf = blockIdx.y;                    // block-uniform -> scalar weight loads
    if (n >= NN) return;
    const int jbase = hf * 32;
    f32x4 row[32];
    const f32x4* fr4 = (const f32x4*)(feat + (long)n * IND);
#pragma unroll
    for (int q = 0; q < 32; ++q) row[q] = __builtin_nontemporal_load(fr4 + q);
    asm volatile("" ::: "memory");          // keep all 32 loads hoisted
    float acc[32];
#pragma unroll
    for (int j = 0; j < 32; ++j) acc[j] = 0.f;
#pragma unroll
    for (int k0 = 0; k0 < 32; ++k0) {
        float f[4] = {row[k0][0], row[k0][1], row[k0][2], row[k0][3]};
#pragma unroll
        for (int kk = 0; kk < 4; ++kk) {
            const float* w = Wt + (k0 * 4 + kk) * HD + jbase;  // wave-uniform
#pragma unroll
            for (int j = 0; j < 32; ++j) acc[j] += f[kk] * w[j];
        }
    }
    // fp16 pack: 32 halves = 4 x 16B stores
    f16x8* d8 = (f16x8*)(feat_h + (long)n * HD + jbase);
#pragma unroll
    for (int q = 0; q < 4; ++q) {
        f16x8 v;
#pragma unroll
        for (int j = 0; j < 8; ++j) v[j] = (_Float16)acc[q * 8 + j];
        d8[q] = v;
    }
    float sh[2], st[2];
#pragma unroll
    for (int hh = 0; hh < 2; ++hh) {
        sh[hh] = 0.f; st[hh] = 0.f;
        int hg = hf * 2 + hh;
#pragma unroll
        for (int d = 0; d < ODD; ++d) {
            float av = acc[hh * ODD + d];
            sh[hh] += av * attn_h[hg * ODD + d];
            st[hh] += av * attn_t[hg * ODD + d];
        }
    }
    eh2[n * 2 + hf] = make_float2(sh[0], sh[1]);
    et2[n * 2 + hf] = make_float2(st[0], st[1]);
}

// ---------------- histogram of dst + per-edge rank --------------------------
__global__ __launch_bounds__(256)
void k_hist(const int* __restrict__ dst, int* __restrict__ deg, int* __restrict__ rank) {
    int e = blockIdx.x * 256 + threadIdx.x;
    if (e < EE) rank[e] = atomicAdd(&deg[dst[e]], 1);
}

// ---------------- two-level exclusive scan of deg -> offs -------------------
__global__ __launch_bounds__(256)
void k_scan1(const int* __restrict__ deg, int* __restrict__ offs, int* __restrict__ part) {
    __shared__ int s[256];
    int t = threadIdx.x, i = blockIdx.x * 256 + t;
    int v = (i < NN) ? deg[i] : 0;
    s[t] = v;
    __syncthreads();
#pragma unroll
    for (int o = 1; o < 256; o <<= 1) {
        int u = (t >= o) ? s[t - o] : 0;
        __syncthreads();
        if (t >= o) s[t] += u;
        __syncthreads();
    }
    if (i < NN) offs[i] = s[t] - v;
    if (t == 255) part[blockIdx.x] = s[255];
}

__global__ __launch_bounds__(256)
void k_scan2(int* __restrict__ part) {
    __shared__ int s[256];
    int t = threadIdx.x;
    int v = (t < NBLK) ? part[t] : 0;
    s[t] = v;
    __syncthreads();
#pragma unroll
    for (int o = 1; o < 256; o <<= 1) {
        int u = (t >= o) ? s[t - o] : 0;
        __syncthreads();
        if (t >= o) s[t] += u;
        __syncthreads();
    }
    if (t < NBLK) part[t] = s[t] - v;
}

__global__ __launch_bounds__(256)
void k_scan3(int* __restrict__ offs, const int* __restrict__ part) {
    int i = blockIdx.x * 256 + threadIdx.x;
    if (i < NN) offs[i] += part[i >> 8];
}

// ------- edge MLP (2 edges/thread): rec scattered DIRECTLY to dst-group slot
// rec4[offs[dst]+rank] = {src, z01(2xf16), z23(2xf16), 0}. Randoms/thread = 4
// (offs x2 + 16B scatter x2) — same transaction count as round-0's perm
// version (scatter width doesn't change line count; rec4 region L2-resident).
// NO node-indexed gathers, NO exp here. perm array eliminated.
__global__ __launch_bounds__(256)
void k_logit2(const float* __restrict__ edge_attr, const int* __restrict__ dst,
              const int* __restrict__ src, const float* __restrict__ w_ee,
              const int* __restrict__ offs, const int* __restrict__ rank,
              i32x4* __restrict__ rec4) {
    int t = blockIdx.x * 256 + threadIdx.x;
    int e0 = t * 2;
    if (e0 >= EE) return;
    i32x2 d2 = *(const i32x2*)(dst + e0);
    i32x2 r2 = *(const i32x2*)(rank + e0);
    i32x2 s2 = *(const i32x2*)(src + e0);
    int o0 = offs[d2[0]], o1 = offs[d2[1]];
    const f32x4* ea = (const f32x4*)(edge_attr + (long)e0 * EDD);
    f32x4 r[16];
#pragma unroll
    for (int c = 0; c < 16; ++c) r[c] = ea[c];       // plain loads
    asm volatile("" ::: "memory");
    const float* f0 = (const float*)&r[0];
    const float* f1 = (const float*)&r[8];
    float z0[NH], z1[NH];
#pragma unroll
    for (int h = 0; h < NH; ++h) {
        float a = 0.f, b = 0.f;
#pragma unroll
        for (int k = 0; k < EDD; ++k) {
            float w = w_ee[h * EDD + k];    // uniform -> s_load
            a += f0[k] * w;
            b += f1[k] * w;
        }
        z0[h] = a; z1[h] = b;
    }
    h2i p01, p23, q01, q23;
    p01.h[0] = (_Float16)z0[0]; p01.h[1] = (_Float16)z0[1];
    p23.h[0] = (_Float16)z0[2]; p23.h[1] = (_Float16)z0[3];
    q01.h[0] = (_Float16)z1[0]; q01.h[1] = (_Float16)z1[1];
    q23.h[0] = (_Float16)z1[2]; q23.h[1] = (_Float16)z1[3];
    i32x4 rc0 = {s2[0], p01.i, p23.i, 0};
    i32x4 rc1 = {s2[1], q01.i, q23.i, 0};
    rec4[o0 + r2[0]] = rc0;                          // 16B scatters (E lines,
    rec4[o1 + r2[1]] = rc1;                          //  L2-merged)
}

// ------- per-dst reduce: COALESCED record read; randoms = eh (L2-hot) + rows
__global__ __launch_bounds__(256)
void k_reduce(const int* __restrict__ offs, const int* __restrict__ deg,
              const i32x4* __restrict__ rec4,
              const float* __restrict__ eh, const float* __restrict__ et,
              const _Float16* __restrict__ feat_h, const float* __restrict__ bias,
              float* __restrict__ out) {
    int wid = (blockIdx.x * 256 + threadIdx.x) >> 6;   // one wave per dst node
    int lane = threadIdx.x & 63;
    if (wid >= NN) return;
    int start = __builtin_amdgcn_readfirstlane(offs[wid]);
    int dn    = __builtin_amdgcn_readfirstlane(deg[wid]);
    int h = lane >> 4;          // head of this lane
    int q = lane & 15;          // edge slot within chunk
    float et_h = et[(long)wid * 4 + h];                // wave-level uniform
    float acc = 0.f, l = 0.f;

    for (int c0 = 0; c0 < dn; c0 += 16) {
        int rem = dn - c0; if (rem > 16) rem = 16;
        int qq = (q < rem) ? q : (rem - 1);            // clamp: stay in-bounds
        i32x4 r = rec4[start + c0 + qq];               // COALESCED 256B/wave
        int   s_q = r.x;
        h2i u; u.i = (h & 2) ? r.z : r.y;
        float z = (float)u.h[h & 1];
        float x = z + eh[(long)s_q * 4 + h] + et_h;    // eh: random 4B, L2-hot
        x = x > 0.f ? x : NEG_SLOPE * x;
        float a_q = (q < rem) ? __expf(x) : 0.f;       // no max-shift: 0.1-scale
        float f[16];
#pragma unroll
        for (int i = 0; i < 16; ++i) {
            int si = __shfl(s_q, i);                   // edge i's src (quad 0)
            f[i] = (float)feat_h[(long)si * HD + lane]; // coalesced 128B row gather
        }
#pragma unroll
        for (int i = 0; i < 16; ++i) {
            float ai = __shfl(a_q, (lane & 48) + i);   // edge i, this lane's head
            l += ai;
            acc += ai * f[i];
        }
    }
    float res = (l > 0.f) ? acc / l : 0.f;
    __builtin_nontemporal_store(res + bias[lane], &out[(long)wid * HD + lane]);
}

extern "C" void kernel_launch(void* const* d_in, const int* in_sizes, int n_in,
                              void* d_out, int out_size, void* d_ws, size_t ws_size,
                              hipStream_t stream) {
    const float* feat      = (const float*)d_in[0];
    const float* edge_attr = (const float*)d_in[1];
    const int*   src       = (const int*)d_in[2];
    const int*   dst       = (const int*)d_in[3];
    const float* W_fc      = (const float*)d_in[4];
    const float* W_edge    = (const float*)d_in[5];
    const float* attn_h    = (const float*)d_in[6];
    const float* attn_t    = (const float*)d_in[7];
    const float* attn_e    = (const float*)d_in[8];
    const float* bias      = (const float*)d_in[9];
    float* out             = (float*)d_out;

    float* ws        = (float*)d_ws;
    i32x4*  rec4     = (i32x4*)ws;                     // E*16B (12.8 MB)
    float4* eh4      = (float4*)(rec4 + EE);           // N*4
    float4* et4      = eh4 + NN;                       // N*4
    _Float16* feat_h = (_Float16*)(et4 + NN);          // N*64 halves (6.4 MB)
    float*  Wt       = (float*)(feat_h + (long)NN * HD); // 8192
    float*  w_ee     = Wt + HD * IND;                  // 128
    int*    rank     = (int*)(w_ee + NH * EDD);        // E
    int*    deg      = rank + EE;                      // N
    int*    offs     = deg + NN;                       // N
    int*    part     = offs + NN;                      // NBLK
    // total ~ 26 MB of d_ws

    k_init_prep<<<NBLK, 256, 0, stream>>>(deg, W_fc, W_edge, attn_e, Wt, w_ee);
    dim3 ngrid(NBLK, 2);
    k_node<<<ngrid, 256, 0, stream>>>(feat, Wt, attn_h, attn_t, feat_h,
                                      (float2*)eh4, (float2*)et4);
    k_hist<<<(EE + 255) / 256, 256, 0, stream>>>(dst, deg, rank);
    k_scan1<<<NBLK, 256, 0, stream>>>(deg, offs, part);
    k_scan2<<<1, 256, 0, stream>>>(part);
    k_scan3<<<NBLK, 256, 0, stream>>>(offs, part);
    k_logit2<<<(EE / 2 + 255) / 256, 256, 0, stream>>>(edge_attr, dst, src, w_ee,
                                                       offs, rank, rec4);
    k_reduce<<<(NN * 64 + 255) / 256, 256, 0, stream>>>(offs, deg, rec4,
                                                        (const float*)eh4,
                                                        (const float*)et4,
                                                        feat_h, bias, out);
}

// Round 8
// 331.238 us; speedup vs baseline: 1.2275x; 1.0509x over previous
//
#include <hip/hip_runtime.h>

#define NN 50000
#define EE 800000
#define IND 128
#define EDD 32
#define ODD 16
#define NH 4
#define HD 64
#define NEG_SLOPE 0.2f
#define NBLK ((NN + 255) / 256)   // 196 scan blocks

typedef float  f32x4 __attribute__((ext_vector_type(4)));
typedef int    i32x2 __attribute__((ext_vector_type(2)));
typedef int    i32x4 __attribute__((ext_vector_type(4)));
typedef _Float16 f16x8 __attribute__((ext_vector_type(8)));

union h2i { int i; _Float16 h[2]; };

// ---------------- init+prep fused: deg=0; Wt transpose; w_ee fold ----------
__global__ __launch_bounds__(256)
void k_init_prep(int* __restrict__ deg, const float* __restrict__ W_fc,
                 const float* __restrict__ W_edge, const float* __restrict__ attn_e,
                 float* __restrict__ Wt, float* __restrict__ w_ee) {
    int i = blockIdx.x * 256 + threadIdx.x;
    if (i < NN) deg[i] = 0;
    if (i < HD * IND) {
        int k = i >> 6, j = i & 63;
        Wt[i] = W_fc[j * IND + k];
    }
    if (i < NH * EDD) {
        int h = i >> 5, k = i & 31;
        float s = 0.f;
        for (int d = 0; d < ODD; ++d)
            s += W_edge[(h * ODD + d) * EDD + k] * attn_e[h * ODD + d];
        w_ee[i] = s;
    }
}

// ------- node projection: gridDim.y=2 halves (block-uniform -> s_load weights)
// ------- plain feat loads (y=1 half re-reads via L2/L3); fp16 output rows
__global__ __launch_bounds__(256)
void k_node(const float* __restrict__ feat, const float* __restrict__ Wt,
            const float* __restrict__ attn_h, const float* __restrict__ attn_t,
            _Float16* __restrict__ feat_h, float2* __restrict__ eh2,
            float2* __restrict__ et2) {
    int n = blockIdx.x * 256 + threadIdx.x;
    int hf = blockIdx.y;                    // block-uniform -> scalar weight loads
    if (n >= NN) return;
    const int jbase = hf * 32;
    f32x4 row[32];
    const f32x4* fr4 = (const f32x4*)(feat + (long)n * IND);
#pragma unroll
    for (int q = 0; q < 32; ++q) row[q] = fr4[q];
    asm volatile("" ::: "memory");          // keep all 32 loads hoisted
    float acc[32];
#pragma unroll
    for (int j = 0; j < 32; ++j) acc[j] = 0.f;
#pragma unroll
    for (int k0 = 0; k0 < 32; ++k0) {
        float f[4] = {row[k0][0], row[k0][1], row[k0][2], row[k0][3]};
#pragma unroll
        for (int kk = 0; kk < 4; ++kk) {
            const float* w = Wt + (k0 * 4 + kk) * HD + jbase;  // wave-uniform
#pragma unroll
            for (int j = 0; j < 32; ++j) acc[j] += f[kk] * w[j];
        }
    }
    // fp16 pack: 32 halves = 4 x 16B stores
    f16x8* d8 = (f16x8*)(feat_h + (long)n * HD + jbase);
#pragma unroll
    for (int q = 0; q < 4; ++q) {
        f16x8 v;
#pragma unroll
        for (int j = 0; j < 8; ++j) v[j] = (_Float16)acc[q * 8 + j];
        d8[q] = v;
    }
    float sh[2], st[2];
#pragma unroll
    for (int hh = 0; hh < 2; ++hh) {
        sh[hh] = 0.f; st[hh] = 0.f;
        int hg = hf * 2 + hh;
#pragma unroll
        for (int d = 0; d < ODD; ++d) {
            float av = acc[hh * ODD + d];
            sh[hh] += av * attn_h[hg * ODD + d];
            st[hh] += av * attn_t[hg * ODD + d];
        }
    }
    eh2[n * 2 + hf] = make_float2(sh[0], sh[1]);
    et2[n * 2 + hf] = make_float2(st[0], st[1]);
}

// ---------------- histogram of dst + per-edge rank --------------------------
__global__ __launch_bounds__(256)
void k_hist(const int* __restrict__ dst, int* __restrict__ deg, int* __restrict__ rank) {
    int e = blockIdx.x * 256 + threadIdx.x;
    if (e < EE) rank[e] = atomicAdd(&deg[dst[e]], 1);
}

// ---------------- two-level exclusive scan of deg -> offs -------------------
__global__ __launch_bounds__(256)
void k_scan1(const int* __restrict__ deg, int* __restrict__ offs, int* __restrict__ part) {
    __shared__ int s[256];
    int t = threadIdx.x, i = blockIdx.x * 256 + t;
    int v = (i < NN) ? deg[i] : 0;
    s[t] = v;
    __syncthreads();
#pragma unroll
    for (int o = 1; o < 256; o <<= 1) {
        int u = (t >= o) ? s[t - o] : 0;
        __syncthreads();
        if (t >= o) s[t] += u;
        __syncthreads();
    }
    if (i < NN) offs[i] = s[t] - v;
    if (t == 255) part[blockIdx.x] = s[255];
}

__global__ __launch_bounds__(256)
void k_scan2(int* __restrict__ part) {
    __shared__ int s[256];
    int t = threadIdx.x;
    int v = (t < NBLK) ? part[t] : 0;
    s[t] = v;
    __syncthreads();
#pragma unroll
    for (int o = 1; o < 256; o <<= 1) {
        int u = (t >= o) ? s[t - o] : 0;
        __syncthreads();
        if (t >= o) s[t] += u;
        __syncthreads();
    }
    if (t < NBLK) part[t] = s[t] - v;
}

__global__ __launch_bounds__(256)
void k_scan3(int* __restrict__ offs, const int* __restrict__ part) {
    int i = blockIdx.x * 256 + threadIdx.x;
    if (i < NN) offs[i] += part[i >> 8];
}

// ------- edge MLP, COOPERATIVE octet layout: 8 lanes per edge ---------------
// Wave handles 64 consecutive edges (8 passes x 8 edges). ea loads are
// perfectly coalesced (64 lanes x 16B = 1KB contiguous per instruction).
// Per edge random ops unchanged: 1 offs gather (L2-hot) + 1 16B rec scatter,
// done by the octet leader. z reduced across octet via 3-level shfl_xor.
// E = 800000 = 3125 blocks x 256 threads exactly (no bounds checks).
__global__ __launch_bounds__(256)
void k_logit8(const float* __restrict__ edge_attr, const int* __restrict__ dst,
              const int* __restrict__ src, const float* __restrict__ w_ee,
              const int* __restrict__ offs, const int* __restrict__ rank,
              i32x4* __restrict__ rec4) {
    int tid = threadIdx.x;
    int wave = tid >> 6, lane = tid & 63;
    long wbase = (long)blockIdx.x * 256 + wave * 64;   // first edge of this wave
    // per-edge scalars, coalesced: lane l <-> edge wbase+l
    int dv = dst[wbase + lane];
    int rv = rank[wbase + lane];
    int sv = src[wbase + lane];
    int oct = lane >> 3;        // edge slot within a pass (0..7)
    int ol  = lane & 7;         // dim slot within edge (4 floats each)
    // per-lane weight slice (fixed across passes): w[h][ol*4 .. ol*4+3]
    float wr[NH][4];
#pragma unroll
    for (int h = 0; h < NH; ++h) {
        f32x4 wv = *(const f32x4*)(w_ee + h * EDD + ol * 4);
        wr[h][0] = wv[0]; wr[h][1] = wv[1]; wr[h][2] = wv[2]; wr[h][3] = wv[3];
    }
    // prefetch all 8 passes: 1KB contiguous per load instruction
    f32x4 u[8];
    const f32x4* ea = (const f32x4*)(edge_attr + wbase * EDD);
#pragma unroll
    for (int p = 0; p < 8; ++p) u[p] = ea[p * 64 + lane];
    asm volatile("" ::: "memory");
#pragma unroll
    for (int p = 0; p < 8; ++p) {
        float z[NH];
#pragma unroll
        for (int h = 0; h < NH; ++h)
            z[h] = u[p][0] * wr[h][0] + u[p][1] * wr[h][1]
                 + u[p][2] * wr[h][2] + u[p][3] * wr[h][3];
#pragma unroll
        for (int h = 0; h < NH; ++h) {      // octet butterfly reduce
            z[h] += __shfl_xor(z[h], 1);
            z[h] += __shfl_xor(z[h], 2);
            z[h] += __shfl_xor(z[h], 4);
        }
        int ei   = p * 8 + oct;             // edge slot within wave
        int lsrc = __shfl(sv, ei);
        int ld   = __shfl(dv, ei);
        int lr   = __shfl(rv, ei);
        if (ol == 0) {                      // octet leader: gather + scatter
            h2i z01, z23;
            z01.h[0] = (_Float16)z[0]; z01.h[1] = (_Float16)z[1];
            z23.h[0] = (_Float16)z[2]; z23.h[1] = (_Float16)z[3];
            i32x4 rc = {lsrc, z01.i, z23.i, 0};
            rec4[offs[ld] + lr] = rc;
        }
    }
}

// ------- per-dst reduce: COALESCED record read; randoms = eh (L2-hot) + rows
__global__ __launch_bounds__(256)
void k_reduce(const int* __restrict__ offs, const int* __restrict__ deg,
              const i32x4* __restrict__ rec4,
              const float* __restrict__ eh, const float* __restrict__ et,
              const _Float16* __restrict__ feat_h, const float* __restrict__ bias,
              float* __restrict__ out) {
    int wid = (blockIdx.x * 256 + threadIdx.x) >> 6;   // one wave per dst node
    int lane = threadIdx.x & 63;
    if (wid >= NN) return;
    int start = __builtin_amdgcn_readfirstlane(offs[wid]);
    int dn    = __builtin_amdgcn_readfirstlane(deg[wid]);
    int h = lane >> 4;          // head of this lane
    int q = lane & 15;          // edge slot within chunk
    float et_h = et[(long)wid * 4 + h];                // wave-level uniform
    float acc = 0.f, l = 0.f;

    for (int c0 = 0; c0 < dn; c0 += 16) {
        int rem = dn - c0; if (rem > 16) rem = 16;
        int qq = (q < rem) ? q : (rem - 1);            // clamp: stay in-bounds
        i32x4 r = rec4[start + c0 + qq];               // COALESCED 256B/wave
        int   s_q = r.x;
        h2i u; u.i = (h & 2) ? r.z : r.y;
        float z = (float)u.h[h & 1];
        float x = z + eh[(long)s_q * 4 + h] + et_h;    // eh: random 4B, L2-hot
        x = x > 0.f ? x : NEG_SLOPE * x;
        float a_q = (q < rem) ? __expf(x) : 0.f;       // no max-shift: 0.1-scale
        float f[16];
#pragma unroll
        for (int i = 0; i < 16; ++i) {
            int si = __shfl(s_q, i);                   // edge i's src (quad 0)
            f[i] = (float)feat_h[(long)si * HD + lane]; // coalesced 128B row gather
        }
#pragma unroll
        for (int i = 0; i < 16; ++i) {
            float ai = __shfl(a_q, (lane & 48) + i);   // edge i, this lane's head
            l += ai;
            acc += ai * f[i];
        }
    }
    float res = (l > 0.f) ? acc / l : 0.f;
    __builtin_nontemporal_store(res + bias[lane], &out[(long)wid * HD + lane]);
}

extern "C" void kernel_launch(void* const* d_in, const int* in_sizes, int n_in,
                              void* d_out, int out_size, void* d_ws, size_t ws_size,
                              hipStream_t stream) {
    const float* feat      = (const float*)d_in[0];
    const float* edge_attr = (const float*)d_in[1];
    const int*   src       = (const int*)d_in[2];
    const int*   dst       = (const int*)d_in[3];
    const float* W_fc      = (const float*)d_in[4];
    const float* W_edge    = (const float*)d_in[5];
    const float* attn_h    = (const float*)d_in[6];
    const float* attn_t    = (const float*)d_in[7];
    const float* attn_e    = (const float*)d_in[8];
    const float* bias      = (const float*)d_in[9];
    float* out             = (float*)d_out;

    float* ws        = (float*)d_ws;
    i32x4*  rec4     = (i32x4*)ws;                     // E*16B (12.8 MB)
    float4* eh4      = (float4*)(rec4 + EE);           // N*4
    float4* et4      = eh4 + NN;                       // N*4
    _Float16* feat_h = (_Float16*)(et4 + NN);          // N*64 halves (6.4 MB)
    float*  Wt       = (float*)(feat_h + (long)NN * HD); // 8192
    float*  w_ee     = Wt + HD * IND;                  // 128
    int*    rank     = (int*)(w_ee + NH * EDD);        // E
    int*    deg      = rank + EE;                      // N
    int*    offs     = deg + NN;                       // N
    int*    part     = offs + NN;                      // NBLK
    // total ~ 26 MB of d_ws

    k_init_prep<<<NBLK, 256, 0, stream>>>(deg, W_fc, W_edge, attn_e, Wt, w_ee);
    dim3 ngrid(NBLK, 2);
    k_node<<<ngrid, 256, 0, stream>>>(feat, Wt, attn_h, attn_t, feat_h,
                                      (float2*)eh4, (float2*)et4);
    k_hist<<<(EE + 255) / 256, 256, 0, stream>>>(dst, deg, rank);
    k_scan1<<<NBLK, 256, 0, stream>>>(deg, offs, part);
    k_scan2<<<1, 256, 0, stream>>>(part);
    k_scan3<<<NBLK, 256, 0, stream>>>(offs, part);
    k_logit8<<<EE / 256, 256, 0, stream>>>(edge_attr, dst, src, w_ee,
                                           offs, rank, rec4);
    k_reduce<<<(NN * 64 + 255) / 256, 256, 0, stream>>>(offs, deg, rec4,
                                                        (const float*)eh4,
                                                        (const float*)et4,
                                                        feat_h, bias, out);
}